// Round 14
// baseline (176.403 us; speedup 1.0000x reference)
//
#include <hip/hip_runtime.h>

#define NPTS 32768
#define KNN 16
#define CH 64
#define CS 8
#define NKP (NPTS*KNN)
#define EPSBN 1e-5f

#define G1 512
#define G2 2048
#define G3 2048
#define G4 2048
#define G5 1024

// ---- DPP cross-lane (VALU pipe, no LDS) ----
template<int CTRL>
__device__ __forceinline__ float dppf(float x){
  int r = __builtin_amdgcn_update_dpp(0, __float_as_int(x), CTRL, 0xf, 0xf, true);
  return __int_as_float(r);
}
__device__ __forceinline__ float dpp_sum16(float x){
  x += dppf<0xB1>(x); x += dppf<0x4E>(x); x += dppf<0x141>(x); x += dppf<0x140>(x);
  return x;
}
__device__ __forceinline__ float dpp_max16(float x){
  x = fmaxf(x, dppf<0xB1>(x)); x = fmaxf(x, dppf<0x4E>(x));
  x = fmaxf(x, dppf<0x141>(x)); x = fmaxf(x, dppf<0x140>(x));
  return x;
}

struct EncParams {
  float q00,q01,q02,q10,q11,q12,q20,q21,q22;
  float pb0,pb1,pb2;
  float ps0,ps1,ps2, pt0,pt1,pt2;
  float v1w, v1b, vs, vt;
};

__device__ __forceinline__ EncParams load_enc(const float* __restrict__ p1w, const float* __restrict__ p1b,
                                              const float* __restrict__ v1w, const float* __restrict__ v1b,
                                              const float* __restrict__ stats) {
  EncParams P;
  P.q00=p1w[0]; P.q01=p1w[1]; P.q02=p1w[2];
  P.q10=p1w[3]; P.q11=p1w[4]; P.q12=p1w[5];
  P.q20=p1w[6]; P.q21=p1w[7]; P.q22=p1w[8];
  P.pb0=p1b[0]; P.pb1=p1b[1]; P.pb2=p1b[2];
  P.ps0=stats[0]; P.ps1=stats[1]; P.ps2=stats[2];
  P.pt0=stats[3]; P.pt1=stats[4]; P.pt2=stats[5];
  P.v1w=v1w[0]; P.v1b=v1b[0]; P.vs=stats[6]; P.vt=stats[7];
  return P;
}

__device__ __forceinline__ void enc_scalars(const EncParams& P, const float* __restrict__ xyz,
                                            const float* __restrict__ vel, int m, int mv,
                                            float xn0, float xn1, float xn2,
                                            float& ry0, float& ry1, float& ry2, float& rv) {
  float pr0 = xyz[m*3+0]-xn0, pr1 = xyz[m*3+1]-xn1, pr2 = xyz[m*3+2]-xn2;
  float y0 = pr0*P.q00 + pr1*P.q10 + pr2*P.q20 + P.pb0;
  float y1 = pr0*P.q01 + pr1*P.q11 + pr2*P.q21 + P.pb1;
  float y2 = pr0*P.q02 + pr1*P.q12 + pr2*P.q22 + P.pb2;
  ry0 = fmaxf(y0*P.ps0+P.pt0, 0.f);
  ry1 = fmaxf(y1*P.ps1+P.pt1, 0.f);
  ry2 = fmaxf(y2*P.ps2+P.pt2, 0.f);
  float vr = vel[mv]*P.v1w + P.v1b;
  rv = fmaxf(vr*P.vs+P.vt, 0.f);
}

// ---------------- K1: scalar-pipe-weight qkv GEMMs + stats wave ----------------
__global__ __launch_bounds__(256) void k1_qkv_stats(
    const float* __restrict__ feat,
    const float* __restrict__ wq, const float* __restrict__ bq,
    const float* __restrict__ wk, const float* __restrict__ bk,
    const float* __restrict__ wv, const float* __restrict__ bv,
    const float* __restrict__ xyz, const float* __restrict__ vel,
    const float* __restrict__ p1w, const float* __restrict__ p1b,
    const float* __restrict__ v1w, const float* __restrict__ v1b,
    const int* __restrict__ idx, const int* __restrict__ idxv,
    float* __restrict__ xq, float* __restrict__ xk, float* __restrict__ xv,
    float* __restrict__ part1)
{
  int tid = threadIdx.x, lane = tid & 63;
  int wu = __builtin_amdgcn_readfirstlane(tid >> 6);
  int row = blockIdx.x*64 + lane;
  if (wu < 3){
    const float* wmat = wu==0? wq : wu==1? wk : wv;
    const float* bias = wu==0? bq : wu==1? bk : bv;
    float* outp = wu==0? xq : wu==1? xk : xv;
    const float4* fp = (const float4*)(feat + (size_t)row*64);
    float acc[64];
    #pragma unroll
    for (int c=0;c<64;c++) acc[c] = 0.f;
    for (int i4=0;i4<16;i4++){
      float4 f = fp[i4];
      #pragma unroll
      for (int ii=0;ii<4;ii++){
        float fv = ii==0?f.x: ii==1?f.y: ii==2?f.z: f.w;
        const float* wrow = wmat + (i4*4+ii)*64;   // uniform -> s_load
        #pragma unroll
        for (int c=0;c<64;c++)
          acc[c] += fv * wrow[c];
      }
    }
    float4* o4 = (float4*)(outp + (size_t)row*64);
    #pragma unroll
    for (int cg=0;cg<16;cg++){
      o4[cg] = make_float4(acc[cg*4+0]+bias[cg*4+0], acc[cg*4+1]+bias[cg*4+1],
                           acc[cg*4+2]+bias[cg*4+2], acc[cg*4+3]+bias[cg*4+3]);
    }
  } else {
    float q00=p1w[0],q01=p1w[1],q02=p1w[2],q10=p1w[3],q11=p1w[4],q12=p1w[5],q20=p1w[6],q21=p1w[7],q22=p1w[8];
    float pb0=p1b[0],pb1=p1b[1],pb2=p1b[2];
    float v1w_=v1w[0], v1b_=v1b[0];
    const int4* ip  = (const int4*)(idx  + (size_t)row*16);
    const int4* ivp = (const int4*)(idxv + (size_t)row*16);
    int4 ia[4], iva[4];
    #pragma unroll
    for (int j=0;j<4;j++){ ia[j]=ip[j]; iva[j]=ivp[j]; }
    float xn0=xyz[row*3], xn1=xyz[row*3+1], xn2=xyz[row*3+2];
    float s0=0,s1=0,s2=0,sv=0,t0=0,t1=0,t2=0,tv=0;
    #pragma unroll
    for (int j=0;j<4;j++){
      int mm[4]  = {ia[j].x, ia[j].y, ia[j].z, ia[j].w};
      int mvv[4] = {iva[j].x, iva[j].y, iva[j].z, iva[j].w};
      #pragma unroll
      for (int u=0;u<4;u++){
        int m = mm[u], mv = mvv[u];
        float pr0=xyz[m*3]-xn0, pr1=xyz[m*3+1]-xn1, pr2=xyz[m*3+2]-xn2;
        float y0 = pr0*q00+pr1*q10+pr2*q20+pb0;
        float y1 = pr0*q01+pr1*q11+pr2*q21+pb1;
        float y2 = pr0*q02+pr1*q12+pr2*q22+pb2;
        float vr = vel[mv]*v1w_ + v1b_;
        s0+=y0; s1+=y1; s2+=y2; sv+=vr;
        t0+=y0*y0; t1+=y1*y1; t2+=y2*y2; tv+=vr*vr;
      }
    }
    #pragma unroll
    for (int msk=1; msk<64; msk<<=1){
      s0 += __shfl_xor(s0,msk); s1 += __shfl_xor(s1,msk); s2 += __shfl_xor(s2,msk); sv += __shfl_xor(sv,msk);
      t0 += __shfl_xor(t0,msk); t1 += __shfl_xor(t1,msk); t2 += __shfl_xor(t2,msk); tv += __shfl_xor(tv,msk);
    }
    if (lane==0){
      float* pp = &part1[blockIdx.x*8];
      pp[0]=s0; pp[1]=s1; pp[2]=s2; pp[3]=sv;
      pp[4]=t0; pp[5]=t1; pp[6]=t2; pp[7]=tv;
    }
  }
}

// ---------------- R1: finalize bn_p (3ch) + bn_v (1ch) ----------------
template<int NB>
__global__ __launch_bounds__(1024) void r1_finalize_t(
    const float* __restrict__ P, const float* __restrict__ pg, const float* __restrict__ pb,
    const float* __restrict__ vg, const float* __restrict__ vb, float* __restrict__ stats)
{
  constexpr int COLG = 2, NSL = 1024/COLG, ITER = (NB+NSL-1)/NSL;
  __shared__ float4 red[1024];
  int t = threadIdx.x; int cg = t % COLG, sl = t / COLG;
  float4 acc = make_float4(0.f,0.f,0.f,0.f);
  const float4* P4 = (const float4*)P;
  #pragma unroll
  for (int j=0;j<ITER;j++){
    int i = sl + j*NSL;
    if (i < NB){
      float4 v = P4[i*COLG + cg];
      acc.x+=v.x; acc.y+=v.y; acc.z+=v.z; acc.w+=v.w;
    }
  }
  red[t] = acc; __syncthreads();
  for (int off = NSL/2; off>0; off>>=1){
    if (sl < off){
      float4 o = red[(sl+off)*COLG + cg];
      acc.x+=o.x; acc.y+=o.y; acc.z+=o.z; acc.w+=o.w;
      red[sl*COLG + cg] = acc;
    }
    __syncthreads();
  }
  if (t<4){
    float s = ((float*)red)[t];
    float q = ((float*)red)[4+t];
    float inv = 1.f/(float)NKP;
    float mean=s*inv, var=q*inv-mean*mean;
    float g = (t<3)? pg[t]:vg[0];
    float b = (t<3)? pb[t]:vb[0];
    float sc = g*rsqrtf(var+EPSBN);
    float sh = b - mean*sc;
    if (t<3){ stats[t]=sc; stats[3+t]=sh; } else { stats[6]=sc; stats[7]=sh; }
  }
}

// ---------------- K1b: materialize renc[p] = (ry0,ry1,ry2,rv) ----------------
__global__ __launch_bounds__(256) void k1b_renc(
    const float* __restrict__ xyz, const float* __restrict__ vel,
    const float* __restrict__ p1w, const float* __restrict__ p1b,
    const float* __restrict__ v1w, const float* __restrict__ v1b,
    const int* __restrict__ idx, const int* __restrict__ idxv,
    const float* __restrict__ stats, float* __restrict__ renc)
{
  EncParams P = load_enc(p1w,p1b,v1w,v1b,stats);
  int p = blockIdx.x*256 + threadIdx.x;      // grid = NKP/256
  int n = p >> 4;
  int m = idx[p], mv = idxv[p];
  float ry0,ry1,ry2,rv;
  enc_scalars(P, xyz, vel, m, mv, xyz[n*3], xyz[n*3+1], xyz[n*3+2], ry0,ry1,ry2,rv);
  ((float4*)renc)[p] = make_float4(ry0,ry1,ry2,rv);
}

// ---------------- generic BN finalize: compile-time sizes, float4 ILP ----------------
template<int NB, int NCH>
__global__ __launch_bounds__(1024) void finalize_bn_t(
    const float* __restrict__ P, float inv,
    const float* __restrict__ g, const float* __restrict__ b,
    float* __restrict__ oscale, float* __restrict__ oshift)
{
  constexpr int COLS = 2*NCH;
  constexpr int COLG = COLS/4;
  constexpr int NSL  = 1024/COLG;
  constexpr int ITER = NB/NSL;
  __shared__ float4 red[1024];
  int t = threadIdx.x; int cg = t % COLG, sl = t / COLG;
  float4 acc = make_float4(0.f,0.f,0.f,0.f);
  const float4* P4 = (const float4*)P;
  #pragma unroll 8
  for (int j=0;j<ITER;j++){
    int i = sl + j*NSL;
    float4 v = P4[i*COLG + cg];
    acc.x+=v.x; acc.y+=v.y; acc.z+=v.z; acc.w+=v.w;
  }
  red[t] = acc; __syncthreads();
  for (int off = NSL/2; off>0; off>>=1){
    if (sl < off){
      float4 o = red[(sl+off)*COLG + cg];
      acc.x+=o.x; acc.y+=o.y; acc.z+=o.z; acc.w+=o.w;
      red[sl*COLG + cg] = acc;
    }
    __syncthreads();
  }
  if (t < NCH){
    float s = ((float*)red)[t];
    float q = ((float*)red)[NCH + t];
    float mean=s*inv, var=q*inv-mean*mean;
    float sc=g[t]*rsqrtf(var+EPSBN);
    oscale[t]=sc; oshift[t]=b[t]-mean*sc;
  }
}

// ---------------- K2: per-channel moments of w = x_k[idx]-x_q+p_enc+v_enc ----------------
__global__ __launch_bounds__(256) void k2_wstats(
    const int* __restrict__ idx, const float* __restrict__ renc,
    const float* __restrict__ p2w, const float* __restrict__ p2b,
    const float* __restrict__ v2w, const float* __restrict__ v2b,
    const float* __restrict__ xq, const float* __restrict__ xk,
    float* __restrict__ part2)
{
  int tid = threadIdx.x;
  int lane = tid & 63, wave = tid >> 6;
  float A = p2w[lane], B = p2w[64+lane], C2 = p2w[128+lane];
  float D = v2w[lane], E = p2b[lane] + v2b[lane];
  const float4* renc4 = (const float4*)renc;
  float sum=0.f, ssq=0.f;
  int gw = blockIdx.x*4 + wave;
  for (int n0 = gw; n0 < NPTS; n0 += G2*4){
    int nu = __builtin_amdgcn_readfirstlane(n0);
    float xqc = xq[nu*64+lane];
    #pragma unroll 4
    for (int k=0;k<KNN;k++){
      int pu = nu*KNN + k;
      int m = idx[pu];
      float4 rr = renc4[pu];
      float e = rr.x*A + rr.y*B + rr.z*C2 + rr.w*D + E;
      float w = xk[m*64+lane] - xqc + e;
      sum += w; ssq += w*w;
    }
  }
  __shared__ float rs[4][64], rq[4][64];
  rs[wave][lane]=sum; rq[wave][lane]=ssq;
  __syncthreads();
  if (tid < 64){
    float s = rs[0][tid]+rs[1][tid]+rs[2][tid]+rs[3][tid];
    float q = rq[0][tid]+rq[1][tid]+rq[2][tid]+rq[3][tid];
    part2[blockIdx.x*128 + tid] = s;
    part2[blockIdx.x*128 + 64 + tid] = q;
  }
}

// ---------------- K3: w1 = relu(bn1(w)) @ w1_w + w1_b ; bn_w2 partials ----------------
// Static 2-iteration unroll; BOTH iterations' idx loads hoisted to entry (mi1 = 4
// extra live VGPRs) so iter-1's xk gather addresses are ready -> removes one
// idx->xk serialization per wave. Everything else identical to the 43us version.
__global__ __launch_bounds__(256) void k3_w1(
    const float* __restrict__ p2w, const float* __restrict__ p2b,
    const float* __restrict__ v2w, const float* __restrict__ v2b,
    const float* __restrict__ w1w, const float* __restrict__ w1b,
    const int* __restrict__ idx, const float* __restrict__ renc,
    const float* __restrict__ xq, const float* __restrict__ xk,
    const float* __restrict__ stats,
    float* __restrict__ w1o, float* __restrict__ part3)
{
  __shared__ __attribute__((aligned(16))) float coef[64*20];
  __shared__ float rs[256], rq[256];
  int tid=threadIdx.x;
  if (tid < 64){
    int c = tid;
    int slot = ((c&7)<<3) | (c>>3);
    float* cf = &coef[slot*20];
    cf[0]=p2w[c]; cf[1]=p2w[64+c]; cf[2]=p2w[128+c];
    cf[3]=v2w[c]; cf[4]=p2b[c]+v2b[c];
    cf[5]=stats[8+c]; cf[6]=stats[72+c];
    #pragma unroll
    for (int j=0;j<8;j++) cf[7+j]=w1w[c*8+j];
    #pragma unroll
    for (int j=15;j<20;j++) cf[j]=0.f;
  }
  __syncthreads();
  int lane=tid&63, wave=tid>>6;
  int sl = lane&7, sp = lane>>3;
  bool p4 = (sl&4)==0, p1 = (sl&1)==0, p2 = (sl&2)==0;
  int jmap = (sl&4) | ((sl&1)<<1) | ((sl&2)>>1);
  float w1b_l = w1b[jmap];
  const float4* renc4=(const float4*)renc;
  const float4* xk4=(const float4*)xk;
  const float4* xq4=(const float4*)xq;
  float ssum=0.f, sqq=0.f;
  constexpr int PSTRIDE = (G3*4)*32;           // NKP/32 / (G3*4) == 2 iterations
  int pbase0 = (blockIdx.x*4 + wave)*32 + sp*4;
  int4 mi0 = *(const int4*)&idx[pbase0];
  int4 mi1 = *(const int4*)&idx[pbase0 + PSTRIDE];

#define K3_ITER(PBASE, MI)                                                     \
  {                                                                            \
    int pbase = (PBASE);                                                       \
    int n = pbase >> 4;                                                        \
    float4 xkv4[8];                                                            \
    {                                                                          \
      int mm0=(MI).x, mm1=(MI).y, mm2=(MI).z, mm3=(MI).w;                      \
      xkv4[0]=xk4[mm0*16+sl*2]; xkv4[1]=xk4[mm0*16+sl*2+1];                    \
      xkv4[2]=xk4[mm1*16+sl*2]; xkv4[3]=xk4[mm1*16+sl*2+1];                    \
      xkv4[4]=xk4[mm2*16+sl*2]; xkv4[5]=xk4[mm2*16+sl*2+1];                    \
      xkv4[6]=xk4[mm3*16+sl*2]; xkv4[7]=xk4[mm3*16+sl*2+1];                    \
    }                                                                          \
    float4 rrs[4] = {renc4[pbase+0], renc4[pbase+1], renc4[pbase+2], renc4[pbase+3]}; \
    float4 xqa = xq4[n*16 + sl*2], xqb = xq4[n*16 + sl*2 + 1];                 \
    float xqv[8] = {xqa.x,xqa.y,xqa.z,xqa.w, xqb.x,xqb.y,xqb.z,xqb.w};         \
    float xkv[4][8];                                                           \
    _Pragma("unroll")                                                          \
    for (int u=0;u<4;u++){                                                     \
      xkv[u][0]=xkv4[u*2].x; xkv[u][1]=xkv4[u*2].y;                            \
      xkv[u][2]=xkv4[u*2].z; xkv[u][3]=xkv4[u*2].w;                            \
      xkv[u][4]=xkv4[u*2+1].x; xkv[u][5]=xkv4[u*2+1].y;                        \
      xkv[u][6]=xkv4[u*2+1].z; xkv[u][7]=xkv4[u*2+1].w;                        \
    }                                                                          \
    float h[4][8];                                                             \
    _Pragma("unroll")                                                          \
    for (int u=0;u<4;u++){                                                     \
      _Pragma("unroll")                                                        \
      for (int j=0;j<8;j++) h[u][j]=0.f;                                       \
    }                                                                          \
    _Pragma("unroll")                                                          \
    for (int r=0;r<8;r++){                                                     \
      const float* cf = &coef[(r*8+sl)*20];                                    \
      float4 ca = *(const float4*)(cf+0);                                      \
      float4 cb = *(const float4*)(cf+4);                                      \
      float4 cc = *(const float4*)(cf+8);                                      \
      float4 cd = *(const float4*)(cf+12);                                     \
      _Pragma("unroll")                                                        \
      for (int u=0;u<4;u++){                                                   \
        float e = rrs[u].x*ca.x + rrs[u].y*ca.y + rrs[u].z*ca.z + rrs[u].w*ca.w + cb.x; \
        float w = xkv[u][r] - xqv[r] + e;                                      \
        float rw = fmaxf(w*cb.y + cb.z, 0.f);                                  \
        h[u][0] += rw*cb.w; h[u][1] += rw*cc.x; h[u][2] += rw*cc.y; h[u][3] += rw*cc.z; \
        h[u][4] += rw*cc.w; h[u][5] += rw*cd.x; h[u][6] += rw*cd.y; h[u][7] += rw*cd.z; \
      }                                                                        \
    }                                                                          \
    _Pragma("unroll")                                                          \
    for (int u=0;u<4;u++){                                                     \
      float g0 = (p4? h[u][0]:h[u][4]) + dppf<0x141>(p4? h[u][4]:h[u][0]);     \
      float g1 = (p4? h[u][1]:h[u][5]) + dppf<0x141>(p4? h[u][5]:h[u][1]);     \
      float g2 = (p4? h[u][2]:h[u][6]) + dppf<0x141>(p4? h[u][6]:h[u][2]);     \
      float g3 = (p4? h[u][3]:h[u][7]) + dppf<0x141>(p4? h[u][7]:h[u][3]);     \
      float f0 = (p1? g0:g2) + dppf<0xB1>(p1? g2:g0);                          \
      float f1 = (p1? g1:g3) + dppf<0xB1>(p1? g3:g1);                          \
      float S  = (p2? f0:f1) + dppf<0x4E>(p2? f1:f0);                          \
      float o = S + w1b_l;                                                     \
      w1o[(pbase+u)*8 + jmap] = o;                                             \
      ssum += o; sqq += o*o;                                                   \
    }                                                                          \
  }

  K3_ITER(pbase0, mi0);
  K3_ITER(pbase0 + PSTRIDE, mi1);
#undef K3_ITER

  rs[(tid & ~7) | jmap]=ssum; rq[(tid & ~7) | jmap]=sqq;
  __syncthreads();
  if (tid < 8){
    float s=0.f,q=0.f;
    #pragma unroll 8
    for (int i=0;i<32;i++){ s+=rs[i*8+tid]; q+=rq[i*8+tid]; }
    part3[blockIdx.x*16 + tid] = s;
    part3[blockIdx.x*16 + 8 + tid] = q;
  }
}

// ---------------- K4: bn2 -> w2 -> softmax over K -> grouped weighted sum -> residual ----------------
__global__ __launch_bounds__(256) void k4_agg(
    const float* __restrict__ feat,
    const float* __restrict__ p2w, const float* __restrict__ p2b,
    const float* __restrict__ v2w, const float* __restrict__ v2b,
    const float* __restrict__ w2w, const float* __restrict__ w2b,
    const int* __restrict__ idx, const float* __restrict__ renc,
    const float* __restrict__ xv, const float* __restrict__ w1o,
    const float* __restrict__ stats,
    float* __restrict__ outpre, float* __restrict__ part4)
{
  __shared__ float sm_s[4][16][8];
  __shared__ float rs[4][64], rq[4][64];
  int tid=threadIdx.x, lane=tid&63, wave=tid>>6;
  int kq = lane & 15, jh = lane >> 4;
  float s2[8], t2[8];
  #pragma unroll
  for (int i=0;i<8;i++){ s2[i]=stats[136+i]; t2[i]=stats[144+i]; }
  float w2c0[8], w2c1[8];
  #pragma unroll
  for (int i=0;i<8;i++){ w2c0[i]=w2w[i*8+jh]; w2c1[i]=w2w[i*8+jh+4]; }
  float w2b0=w2b[jh], w2b1=w2b[jh+4];
  float A=p2w[lane], B=p2w[64+lane], C2=p2w[128+lane], D=v2w[lane], E=p2b[lane]+v2b[lane];
  int j = lane & 7;
  const float4* renc4 = (const float4*)renc;
  float sr=0.f, sq2=0.f;
  int gw = blockIdx.x*4 + wave;
  for (int n0 = gw; n0 < NPTS; n0 += G4*4){
    int nu = __builtin_amdgcn_readfirstlane(n0);
    const float* w1p = &w1o[(nu*KNN + kq)*8];
    float4 wa = *(const float4*)w1p;
    float4 wb = *(const float4*)(w1p+4);
    float r0 = fmaxf(wa.x*s2[0]+t2[0],0.f);
    float r1 = fmaxf(wa.y*s2[1]+t2[1],0.f);
    float r2 = fmaxf(wa.z*s2[2]+t2[2],0.f);
    float r3 = fmaxf(wa.w*s2[3]+t2[3],0.f);
    float r4 = fmaxf(wb.x*s2[4]+t2[4],0.f);
    float r5 = fmaxf(wb.y*s2[5]+t2[5],0.f);
    float r6 = fmaxf(wb.z*s2[6]+t2[6],0.f);
    float r7 = fmaxf(wb.w*s2[7]+t2[7],0.f);
    float g0 = r0*w2c0[0]+r1*w2c0[1]+r2*w2c0[2]+r3*w2c0[3]
             + r4*w2c0[4]+r5*w2c0[5]+r6*w2c0[6]+r7*w2c0[7] + w2b0;
    float g1 = r0*w2c1[0]+r1*w2c1[1]+r2*w2c1[2]+r3*w2c1[3]
             + r4*w2c1[4]+r5*w2c1[5]+r6*w2c1[6]+r7*w2c1[7] + w2b1;
    float m0 = dpp_max16(g0), m1 = dpp_max16(g1);
    float e0=__expf(g0-m0), e1=__expf(g1-m1);
    float d0 = dpp_sum16(e0), d1 = dpp_sum16(e1);
    sm_s[wave][kq][jh]   = e0/d0;
    sm_s[wave][kq][jh+4] = e1/d1;
    __asm__ __volatile__("" ::: "memory");
    float acc=0.f;
    #pragma unroll 4
    for (int k=0;k<KNN;k++){
      int pu = nu*KNN+k;
      int m = idx[pu];
      float4 rr = renc4[pu];
      float e = rr.x*A + rr.y*B + rr.z*C2 + rr.w*D + E;
      acc += (xv[m*64+lane] + e) * sm_s[wave][k][j];
    }
    float o = acc + feat[nu*64+lane];
    outpre[nu*64+lane] = o;
    sr += o; sq2 += o*o;
    __asm__ __volatile__("" ::: "memory");
  }
  rs[wave][lane]=sr; rq[wave][lane]=sq2;
  __syncthreads();
  if (tid<64){
    float s=rs[0][tid]+rs[1][tid]+rs[2][tid]+rs[3][tid];
    float q=rq[0][tid]+rq[1][tid]+rq[2][tid]+rq[3][tid];
    part4[blockIdx.x*128+tid]=s;
    part4[blockIdx.x*128+64+tid]=q;
  }
}

// ---------------- K5: out = relu(bn_rho(out_pre)) @ rho_w + rho_b ----------------
__global__ __launch_bounds__(256) void k5_rho(
    const float* __restrict__ outpre, const float* __restrict__ stats,
    const float* __restrict__ rhow, const float* __restrict__ rhob,
    float* __restrict__ out)
{
  __shared__ __attribute__((aligned(16))) float4 lw4[1024];
  __shared__ __attribute__((aligned(16))) float lf[2048];
  float* lw = (float*)lw4;
  int tid=threadIdx.x;
  for (int i=tid;i<1024;i+=256) lw4[i] = ((const float4*)rhow)[i];
  __syncthreads();
  int lane=tid&63, wave=tid>>6;
  int nb = blockIdx.x*32 + wave*8;
  float scl = stats[152+lane], sft = stats[216+lane];
  #pragma unroll
  for (int r=0;r<8;r++){
    float a = outpre[(nb+r)*64+lane];
    lf[wave*512 + r*64 + lane] = fmaxf(a*scl+sft, 0.f);
  }
  float acc[8];
  #pragma unroll
  for (int r=0;r<8;r++) acc[r]=0.f;
  for (int i=0;i<64;i+=4){
    float4 fr[8];
    #pragma unroll
    for (int r=0;r<8;r++) fr[r] = *(const float4*)&lf[wave*512 + r*64 + i];
    #pragma unroll
    for (int ii=0;ii<4;ii++){
      float w_ = lw[(i+ii)*64+lane];
      #pragma unroll
      for (int r=0;r<8;r++){
        float f = ii==0?fr[r].x: ii==1?fr[r].y: ii==2?fr[r].z: fr[r].w;
        acc[r] += f*w_;
      }
    }
  }
  float bl = rhob[lane];
  #pragma unroll
  for (int r=0;r<8;r++) out[(nb+r)*64+lane] = acc[r] + bl;
}

extern "C" void kernel_launch(void* const* d_in, const int* in_sizes, int n_in,
                              void* d_out, int out_size, void* d_ws, size_t ws_size,
                              hipStream_t stream) {
  const float* xyz  = (const float*)d_in[0];
  const float* feat = (const float*)d_in[1];
  const float* vel  = (const float*)d_in[2];
  const float* wq   = (const float*)d_in[3];  const float* bq = (const float*)d_in[4];
  const float* wk   = (const float*)d_in[5];  const float* bk = (const float*)d_in[6];
  const float* wv   = (const float*)d_in[7];  const float* bv = (const float*)d_in[8];
  const float* p1w  = (const float*)d_in[9];  const float* p1b = (const float*)d_in[10];
  const float* pbg  = (const float*)d_in[11]; const float* pbb = (const float*)d_in[12];
  const float* p2w  = (const float*)d_in[13]; const float* p2b = (const float*)d_in[14];
  const float* v1w  = (const float*)d_in[15]; const float* v1b = (const float*)d_in[16];
  const float* vbg  = (const float*)d_in[17]; const float* vbb = (const float*)d_in[18];
  const float* v2w  = (const float*)d_in[19]; const float* v2b = (const float*)d_in[20];
  const float* wbn1g= (const float*)d_in[21]; const float* wbn1b= (const float*)d_in[22];
  const float* w1w  = (const float*)d_in[23]; const float* w1b = (const float*)d_in[24];
  const float* wbn2g= (const float*)d_in[25]; const float* wbn2b= (const float*)d_in[26];
  const float* w2w  = (const float*)d_in[27]; const float* w2b = (const float*)d_in[28];
  const float* rbg  = (const float*)d_in[29]; const float* rbb = (const float*)d_in[30];
  const float* rhow = (const float*)d_in[31]; const float* rhob = (const float*)d_in[32];
  const int* idx    = (const int*)d_in[33];
  const int* idxv   = (const int*)d_in[34];

  float* ws = (float*)d_ws;
  float* xq     = ws;
  float* xk     = xq + (size_t)NPTS*CH;
  float* xv     = xk + (size_t)NPTS*CH;
  float* w1o    = xv + (size_t)NPTS*CH;
  float* outpre = w1o + (size_t)NKP*CS;
  float* renc   = outpre + (size_t)NPTS*CH;
  float* part1  = renc + (size_t)NKP*4;
  float* part2  = part1 + G1*8;
  float* part3  = part2 + (size_t)G2*128;
  float* part4  = part3 + G3*16;
  float* stats  = part4 + (size_t)G4*128;

  k1_qkv_stats<<<dim3(G1), dim3(256), 0, stream>>>(
      feat, wq,bq,wk,bk,wv,bv, xyz, vel, p1w,p1b,v1w,v1b, idx, idxv, xq,xk,xv, part1);
  r1_finalize_t<G1><<<dim3(1), dim3(1024), 0, stream>>>(part1, pbg,pbb, vbg,vbb, stats);
  k1b_renc<<<dim3(NKP/256), dim3(256), 0, stream>>>(
      xyz, vel, p1w,p1b, v1w,v1b, idx, idxv, stats, renc);
  k2_wstats<<<dim3(G2), dim3(256), 0, stream>>>(
      idx, renc, p2w,p2b,v2w,v2b, xq, xk, part2);
  finalize_bn_t<G2,64><<<dim3(1), dim3(1024), 0, stream>>>(
      part2, 1.f/(float)NKP, wbn1g, wbn1b, stats+8, stats+72);
  k3_w1<<<dim3(G3), dim3(256), 0, stream>>>(
      p2w,p2b,v2w,v2b, w1w,w1b, idx, renc, xq, xk, stats, w1o, part3);
  finalize_bn_t<G3,8><<<dim3(1), dim3(1024), 0, stream>>>(
      part3, 1.f/(float)NKP, wbn2g, wbn2b, stats+136, stats+144);
  k4_agg<<<dim3(G4), dim3(256), 0, stream>>>(
      feat, p2w,p2b,v2w,v2b, w2w,w2b, idx, renc, xv, w1o, stats, outpre, part4);
  finalize_bn_t<G4,64><<<dim3(1), dim3(1024), 0, stream>>>(
      part4, 1.f/(float)NPTS, rbg, rbb, stats+152, stats+216);
  k5_rho<<<dim3(G5), dim3(256), 0, stream>>>(outpre, stats, rhow, rhob, (float*)d_out);

  (void)in_sizes; (void)n_in; (void)out_size; (void)ws_size;
}

// Round 15
// 147.266 us; speedup vs baseline: 1.1978x; 1.1978x over previous
//
#include <hip/hip_runtime.h>

#define NPTS 32768
#define KNN 16
#define CH 64
#define CS 8
#define NKP (NPTS*KNN)
#define EPSBN 1e-5f

#define G1 512
#define G2 2048
#define G3 2048
#define G4 2048
#define G5 1024

// ---- DPP cross-lane (VALU pipe, no LDS) ----
template<int CTRL>
__device__ __forceinline__ float dppf(float x){
  int r = __builtin_amdgcn_update_dpp(0, __float_as_int(x), CTRL, 0xf, 0xf, true);
  return __int_as_float(r);
}
__device__ __forceinline__ float dpp_sum16(float x){
  x += dppf<0xB1>(x); x += dppf<0x4E>(x); x += dppf<0x141>(x); x += dppf<0x140>(x);
  return x;
}
__device__ __forceinline__ float dpp_max16(float x){
  x = fmaxf(x, dppf<0xB1>(x)); x = fmaxf(x, dppf<0x4E>(x));
  x = fmaxf(x, dppf<0x141>(x)); x = fmaxf(x, dppf<0x140>(x));
  return x;
}

struct EncParams {
  float q00,q01,q02,q10,q11,q12,q20,q21,q22;
  float pb0,pb1,pb2;
  float ps0,ps1,ps2, pt0,pt1,pt2;
  float v1w, v1b, vs, vt;
};

__device__ __forceinline__ EncParams load_enc(const float* __restrict__ p1w, const float* __restrict__ p1b,
                                              const float* __restrict__ v1w, const float* __restrict__ v1b,
                                              const float* __restrict__ stats) {
  EncParams P;
  P.q00=p1w[0]; P.q01=p1w[1]; P.q02=p1w[2];
  P.q10=p1w[3]; P.q11=p1w[4]; P.q12=p1w[5];
  P.q20=p1w[6]; P.q21=p1w[7]; P.q22=p1w[8];
  P.pb0=p1b[0]; P.pb1=p1b[1]; P.pb2=p1b[2];
  P.ps0=stats[0]; P.ps1=stats[1]; P.ps2=stats[2];
  P.pt0=stats[3]; P.pt1=stats[4]; P.pt2=stats[5];
  P.v1w=v1w[0]; P.v1b=v1b[0]; P.vs=stats[6]; P.vt=stats[7];
  return P;
}

__device__ __forceinline__ void enc_scalars(const EncParams& P, const float* __restrict__ xyz,
                                            const float* __restrict__ vel, int m, int mv,
                                            float xn0, float xn1, float xn2,
                                            float& ry0, float& ry1, float& ry2, float& rv) {
  float pr0 = xyz[m*3+0]-xn0, pr1 = xyz[m*3+1]-xn1, pr2 = xyz[m*3+2]-xn2;
  float y0 = pr0*P.q00 + pr1*P.q10 + pr2*P.q20 + P.pb0;
  float y1 = pr0*P.q01 + pr1*P.q11 + pr2*P.q21 + P.pb1;
  float y2 = pr0*P.q02 + pr1*P.q12 + pr2*P.q22 + P.pb2;
  ry0 = fmaxf(y0*P.ps0+P.pt0, 0.f);
  ry1 = fmaxf(y1*P.ps1+P.pt1, 0.f);
  ry2 = fmaxf(y2*P.ps2+P.pt2, 0.f);
  float vr = vel[mv]*P.v1w + P.v1b;
  rv = fmaxf(vr*P.vs+P.vt, 0.f);
}

// ---------------- K1: LDS-staged qkv GEMMs (16 rows/wave) + bn_p/bn_v stats tail ----------------
__global__ __launch_bounds__(256, 2) void k1_qkv_stats(
    const float* __restrict__ feat,
    const float* __restrict__ wq, const float* __restrict__ bq,
    const float* __restrict__ wk, const float* __restrict__ bk,
    const float* __restrict__ wv, const float* __restrict__ bv,
    const float* __restrict__ xyz, const float* __restrict__ vel,
    const float* __restrict__ p1w, const float* __restrict__ p1b,
    const float* __restrict__ v1w, const float* __restrict__ v1b,
    const int* __restrict__ idx, const int* __restrict__ idxv,
    float* __restrict__ xq, float* __restrict__ xk, float* __restrict__ xv,
    float* __restrict__ part1)
{
  __shared__ __attribute__((aligned(16))) float4 lw4[3072];  // wq|wk|wv, [i][c]
  __shared__ __attribute__((aligned(16))) float4 lf4[1024];  // 64 rows x 64
  __shared__ float red1[32];
  float* lw = (float*)lw4;
  float* lf = (float*)lf4;
  int tid = threadIdx.x;
  #pragma unroll
  for (int j=0;j<12;j++){
    int i = tid + j*256;
    float4 v;
    if (i < 1024) v = ((const float4*)wq)[i];
    else if (i < 2048) v = ((const float4*)wk)[i-1024];
    else v = ((const float4*)wv)[i-2048];
    lw4[i] = v;
  }
  {
    const float4* f4 = (const float4*)(feat + (size_t)blockIdx.x*64*64);
    #pragma unroll
    for (int j=0;j<4;j++) lf4[tid + j*256] = f4[tid + j*256];
  }
  __syncthreads();
  int lane = tid & 63, wave = tid >> 6;
  int rb = wave*16;
  int nb = blockIdx.x*64 + rb;
  float aq[16], ak[16], av[16];
  #pragma unroll
  for (int r=0;r<16;r++){ aq[r]=0.f; ak[r]=0.f; av[r]=0.f; }
  for (int i=0;i<64;i+=4){
    float4 fr[16];
    #pragma unroll
    for (int r=0;r<16;r++) fr[r] = *(const float4*)&lf[(rb+r)*64 + i];
    #pragma unroll
    for (int ii=0;ii<4;ii++){
      float wqi = lw[(i+ii)*64+lane];
      float wki = lw[4096+(i+ii)*64+lane];
      float wvi = lw[8192+(i+ii)*64+lane];
      #pragma unroll
      for (int r=0;r<16;r++){
        float f = ii==0?fr[r].x: ii==1?fr[r].y: ii==2?fr[r].z: fr[r].w;
        aq[r] += f*wqi; ak[r] += f*wki; av[r] += f*wvi;
      }
    }
  }
  float bql=bq[lane], bkl=bk[lane], bvl=bv[lane];
  #pragma unroll
  for (int r=0;r<16;r++){
    size_t row = (size_t)(nb + r);
    xq[row*64+lane] = aq[r]+bql;
    xk[row*64+lane] = ak[r]+bkl;
    xv[row*64+lane] = av[r]+bvl;
  }
  // ---- bn_p / bn_v raw stats over this block's 64 rows x 16 pairs ----
  float q00=p1w[0],q01=p1w[1],q02=p1w[2],q10=p1w[3],q11=p1w[4],q12=p1w[5],q20=p1w[6],q21=p1w[7],q22=p1w[8];
  float pb0=p1b[0],pb1=p1b[1],pb2=p1b[2];
  float v1w_=v1w[0], v1b_=v1b[0];
  float s0=0,s1=0,s2=0,sv=0,t0=0,t1=0,t2=0,tv=0;
  #pragma unroll
  for (int rep=0; rep<4; rep++){
    int p = blockIdx.x*1024 + rep*256 + tid;
    int n = p >> 4;
    int m = idx[p], mv = idxv[p];
    float xn0=xyz[n*3], xn1=xyz[n*3+1], xn2=xyz[n*3+2];
    float pr0=xyz[m*3]-xn0, pr1=xyz[m*3+1]-xn1, pr2=xyz[m*3+2]-xn2;
    float y0 = pr0*q00+pr1*q10+pr2*q20+pb0;
    float y1 = pr0*q01+pr1*q11+pr2*q21+pb1;
    float y2 = pr0*q02+pr1*q12+pr2*q22+pb2;
    float vr = vel[mv]*v1w_ + v1b_;
    s0+=y0; s1+=y1; s2+=y2; sv+=vr;
    t0+=y0*y0; t1+=y1*y1; t2+=y2*y2; tv+=vr*vr;
  }
  #pragma unroll
  for (int msk=1; msk<64; msk<<=1){
    s0 += __shfl_xor(s0,msk); s1 += __shfl_xor(s1,msk); s2 += __shfl_xor(s2,msk); sv += __shfl_xor(sv,msk);
    t0 += __shfl_xor(t0,msk); t1 += __shfl_xor(t1,msk); t2 += __shfl_xor(t2,msk); tv += __shfl_xor(tv,msk);
  }
  if (lane==0){
    red1[wave*8+0]=s0; red1[wave*8+1]=s1; red1[wave*8+2]=s2; red1[wave*8+3]=sv;
    red1[wave*8+4]=t0; red1[wave*8+5]=t1; red1[wave*8+6]=t2; red1[wave*8+7]=tv;
  }
  __syncthreads();
  if (tid < 8){
    float a = red1[tid] + red1[8+tid] + red1[16+tid] + red1[24+tid];
    part1[blockIdx.x*8 + tid] = a;
  }
}

// ---------------- R1: finalize bn_p (3ch) + bn_v (1ch) ----------------
template<int NB>
__global__ __launch_bounds__(1024) void r1_finalize_t(
    const float* __restrict__ P, const float* __restrict__ pg, const float* __restrict__ pb,
    const float* __restrict__ vg, const float* __restrict__ vb, float* __restrict__ stats)
{
  constexpr int COLG = 2, NSL = 1024/COLG, ITER = (NB+NSL-1)/NSL;
  __shared__ float4 red[1024];
  int t = threadIdx.x; int cg = t % COLG, sl = t / COLG;
  float4 acc = make_float4(0.f,0.f,0.f,0.f);
  const float4* P4 = (const float4*)P;
  #pragma unroll
  for (int j=0;j<ITER;j++){
    int i = sl + j*NSL;
    if (i < NB){
      float4 v = P4[i*COLG + cg];
      acc.x+=v.x; acc.y+=v.y; acc.z+=v.z; acc.w+=v.w;
    }
  }
  red[t] = acc; __syncthreads();
  for (int off = NSL/2; off>0; off>>=1){
    if (sl < off){
      float4 o = red[(sl+off)*COLG + cg];
      acc.x+=o.x; acc.y+=o.y; acc.z+=o.z; acc.w+=o.w;
      red[sl*COLG + cg] = acc;
    }
    __syncthreads();
  }
  if (t<4){
    float s = ((float*)red)[t];
    float q = ((float*)red)[4+t];
    float inv = 1.f/(float)NKP;
    float mean=s*inv, var=q*inv-mean*mean;
    float g = (t<3)? pg[t]:vg[0];
    float b = (t<3)? pb[t]:vb[0];
    float sc = g*rsqrtf(var+EPSBN);
    float sh = b - mean*sc;
    if (t<3){ stats[t]=sc; stats[3+t]=sh; } else { stats[6]=sc; stats[7]=sh; }
  }
}

// ---------------- K1b: materialize renc[p] = (ry0,ry1,ry2,rv) ----------------
__global__ __launch_bounds__(256) void k1b_renc(
    const float* __restrict__ xyz, const float* __restrict__ vel,
    const float* __restrict__ p1w, const float* __restrict__ p1b,
    const float* __restrict__ v1w, const float* __restrict__ v1b,
    const int* __restrict__ idx, const int* __restrict__ idxv,
    const float* __restrict__ stats, float* __restrict__ renc)
{
  EncParams P = load_enc(p1w,p1b,v1w,v1b,stats);
  int p = blockIdx.x*256 + threadIdx.x;      // grid = NKP/256
  int n = p >> 4;
  int m = idx[p], mv = idxv[p];
  float ry0,ry1,ry2,rv;
  enc_scalars(P, xyz, vel, m, mv, xyz[n*3], xyz[n*3+1], xyz[n*3+2], ry0,ry1,ry2,rv);
  ((float4*)renc)[p] = make_float4(ry0,ry1,ry2,rv);
}

// ---------------- generic BN finalize: compile-time sizes, float4 ILP ----------------
template<int NB, int NCH>
__global__ __launch_bounds__(1024) void finalize_bn_t(
    const float* __restrict__ P, float inv,
    const float* __restrict__ g, const float* __restrict__ b,
    float* __restrict__ oscale, float* __restrict__ oshift)
{
  constexpr int COLS = 2*NCH;
  constexpr int COLG = COLS/4;
  constexpr int NSL  = 1024/COLG;
  constexpr int ITER = NB/NSL;
  __shared__ float4 red[1024];
  int t = threadIdx.x; int cg = t % COLG, sl = t / COLG;
  float4 acc = make_float4(0.f,0.f,0.f,0.f);
  const float4* P4 = (const float4*)P;
  #pragma unroll 8
  for (int j=0;j<ITER;j++){
    int i = sl + j*NSL;
    float4 v = P4[i*COLG + cg];
    acc.x+=v.x; acc.y+=v.y; acc.z+=v.z; acc.w+=v.w;
  }
  red[t] = acc; __syncthreads();
  for (int off = NSL/2; off>0; off>>=1){
    if (sl < off){
      float4 o = red[(sl+off)*COLG + cg];
      acc.x+=o.x; acc.y+=o.y; acc.z+=o.z; acc.w+=o.w;
      red[sl*COLG + cg] = acc;
    }
    __syncthreads();
  }
  if (t < NCH){
    float s = ((float*)red)[t];
    float q = ((float*)red)[NCH + t];
    float mean=s*inv, var=q*inv-mean*mean;
    float sc=g[t]*rsqrtf(var+EPSBN);
    oscale[t]=sc; oshift[t]=b[t]-mean*sc;
  }
}

// ---------------- K2: per-channel moments of w = x_k[idx]-x_q+p_enc+v_enc ----------------
__global__ __launch_bounds__(256) void k2_wstats(
    const int* __restrict__ idx, const float* __restrict__ renc,
    const float* __restrict__ p2w, const float* __restrict__ p2b,
    const float* __restrict__ v2w, const float* __restrict__ v2b,
    const float* __restrict__ xq, const float* __restrict__ xk,
    float* __restrict__ part2)
{
  int tid = threadIdx.x;
  int lane = tid & 63, wave = tid >> 6;
  float A = p2w[lane], B = p2w[64+lane], C2 = p2w[128+lane];
  float D = v2w[lane], E = p2b[lane] + v2b[lane];
  const float4* renc4 = (const float4*)renc;
  float sum=0.f, ssq=0.f;
  int gw = blockIdx.x*4 + wave;
  for (int n0 = gw; n0 < NPTS; n0 += G2*4){
    int nu = __builtin_amdgcn_readfirstlane(n0);
    float xqc = xq[nu*64+lane];
    #pragma unroll 4
    for (int k=0;k<KNN;k++){
      int pu = nu*KNN + k;
      int m = idx[pu];
      float4 rr = renc4[pu];
      float e = rr.x*A + rr.y*B + rr.z*C2 + rr.w*D + E;
      float w = xk[m*64+lane] - xqc + e;
      sum += w; ssq += w*w;
    }
  }
  __shared__ float rs[4][64], rq[4][64];
  rs[wave][lane]=sum; rq[wave][lane]=ssq;
  __syncthreads();
  if (tid < 64){
    float s = rs[0][tid]+rs[1][tid]+rs[2][tid]+rs[3][tid];
    float q = rq[0][tid]+rq[1][tid]+rq[2][tid]+rq[3][tid];
    part2[blockIdx.x*128 + tid] = s;
    part2[blockIdx.x*128 + 64 + tid] = q;
  }
}

// ---------------- K3: w1 = relu(bn1(w)) @ w1_w + w1_b ; bn_w2 partials ----------------
__global__ __launch_bounds__(256) void k3_w1(
    const float* __restrict__ p2w, const float* __restrict__ p2b,
    const float* __restrict__ v2w, const float* __restrict__ v2b,
    const float* __restrict__ w1w, const float* __restrict__ w1b,
    const int* __restrict__ idx, const float* __restrict__ renc,
    const float* __restrict__ xq, const float* __restrict__ xk,
    const float* __restrict__ stats,
    float* __restrict__ w1o, float* __restrict__ part3)
{
  __shared__ __attribute__((aligned(16))) float coef[64*20];
  __shared__ float rs[256], rq[256];
  int tid=threadIdx.x;
  if (tid < 64){
    int c = tid;
    int slot = ((c&7)<<3) | (c>>3);
    float* cf = &coef[slot*20];
    cf[0]=p2w[c]; cf[1]=p2w[64+c]; cf[2]=p2w[128+c];
    cf[3]=v2w[c]; cf[4]=p2b[c]+v2b[c];
    cf[5]=stats[8+c]; cf[6]=stats[72+c];
    #pragma unroll
    for (int j=0;j<8;j++) cf[7+j]=w1w[c*8+j];
    #pragma unroll
    for (int j=15;j<20;j++) cf[j]=0.f;
  }
  __syncthreads();
  int lane=tid&63, wave=tid>>6;
  int sl = lane&7, sp = lane>>3;
  bool p4 = (sl&4)==0, p1 = (sl&1)==0, p2 = (sl&2)==0;
  int jmap = (sl&4) | ((sl&1)<<1) | ((sl&2)>>1);
  float w1b_l = w1b[jmap];
  const float4* renc4=(const float4*)renc;
  const float4* xk4=(const float4*)xk;
  const float4* xq4=(const float4*)xq;
  float ssum=0.f, sqq=0.f;
  int gw = blockIdx.x*4 + wave;
  for (int it = gw; it < NKP/32; it += G3*4){
    int pbase = it*32 + sp*4;
    int n = pbase >> 4;
    int4 mi = *(const int4*)&idx[pbase];
    float4 rrs[4] = {renc4[pbase+0], renc4[pbase+1], renc4[pbase+2], renc4[pbase+3]};
    float4 xqa = xq4[n*16 + sl*2], xqb = xq4[n*16 + sl*2 + 1];
    float xqv[8] = {xqa.x,xqa.y,xqa.z,xqa.w, xqb.x,xqb.y,xqb.z,xqb.w};
    float xkv[4][8];
    {
      int mm[4] = {mi.x, mi.y, mi.z, mi.w};
      #pragma unroll
      for (int u=0;u<4;u++){
        float4 a = xk4[mm[u]*16 + sl*2], b = xk4[mm[u]*16 + sl*2 + 1];
        xkv[u][0]=a.x; xkv[u][1]=a.y; xkv[u][2]=a.z; xkv[u][3]=a.w;
        xkv[u][4]=b.x; xkv[u][5]=b.y; xkv[u][6]=b.z; xkv[u][7]=b.w;
      }
    }
    float h[4][8];
    #pragma unroll
    for (int u=0;u<4;u++)
      #pragma unroll
      for (int j=0;j<8;j++) h[u][j]=0.f;
    #pragma unroll
    for (int r=0;r<8;r++){
      const float* cf = &coef[(r*8+sl)*20];
      float4 ca = *(const float4*)(cf+0);
      float4 cb = *(const float4*)(cf+4);
      float4 cc = *(const float4*)(cf+8);
      float4 cd = *(const float4*)(cf+12);
      #pragma unroll
      for (int u=0;u<4;u++){
        float e = rrs[u].x*ca.x + rrs[u].y*ca.y + rrs[u].z*ca.z + rrs[u].w*ca.w + cb.x;
        float w = xkv[u][r] - xqv[r] + e;
        float rw = fmaxf(w*cb.y + cb.z, 0.f);
        h[u][0] += rw*cb.w; h[u][1] += rw*cc.x; h[u][2] += rw*cc.y; h[u][3] += rw*cc.z;
        h[u][4] += rw*cc.w; h[u][5] += rw*cd.x; h[u][6] += rw*cd.y; h[u][7] += rw*cd.z;
      }
    }
    #pragma unroll
    for (int u=0;u<4;u++){
      float g0 = (p4? h[u][0]:h[u][4]) + dppf<0x141>(p4? h[u][4]:h[u][0]);
      float g1 = (p4? h[u][1]:h[u][5]) + dppf<0x141>(p4? h[u][5]:h[u][1]);
      float g2 = (p4? h[u][2]:h[u][6]) + dppf<0x141>(p4? h[u][6]:h[u][2]);
      float g3 = (p4? h[u][3]:h[u][7]) + dppf<0x141>(p4? h[u][7]:h[u][3]);
      float f0 = (p1? g0:g2) + dppf<0xB1>(p1? g2:g0);
      float f1 = (p1? g1:g3) + dppf<0xB1>(p1? g3:g1);
      float S  = (p2? f0:f1) + dppf<0x4E>(p2? f1:f0);
      float o = S + w1b_l;
      w1o[(pbase+u)*8 + jmap] = o;
      ssum += o; sqq += o*o;
    }
  }
  rs[(tid & ~7) | jmap]=ssum; rq[(tid & ~7) | jmap]=sqq;
  __syncthreads();
  if (tid < 8){
    float s=0.f,q=0.f;
    #pragma unroll 8
    for (int i=0;i<32;i++){ s+=rs[i*8+tid]; q+=rq[i*8+tid]; }
    part3[blockIdx.x*16 + tid] = s;
    part3[blockIdx.x*16 + 8 + tid] = q;
  }
}

// ---------------- K4: bn2 -> w2 -> softmax over K -> grouped weighted sum -> residual ----------------
__global__ __launch_bounds__(256) void k4_agg(
    const float* __restrict__ feat,
    const float* __restrict__ p2w, const float* __restrict__ p2b,
    const float* __restrict__ v2w, const float* __restrict__ v2b,
    const float* __restrict__ w2w, const float* __restrict__ w2b,
    const int* __restrict__ idx, const float* __restrict__ renc,
    const float* __restrict__ xv, const float* __restrict__ w1o,
    const float* __restrict__ stats,
    float* __restrict__ outpre, float* __restrict__ part4)
{
  __shared__ float sm_s[4][16][8];
  __shared__ float rs[4][64], rq[4][64];
  int tid=threadIdx.x, lane=tid&63, wave=tid>>6;
  int kq = lane & 15, jh = lane >> 4;
  float s2[8], t2[8];
  #pragma unroll
  for (int i=0;i<8;i++){ s2[i]=stats[136+i]; t2[i]=stats[144+i]; }
  float w2c0[8], w2c1[8];
  #pragma unroll
  for (int i=0;i<8;i++){ w2c0[i]=w2w[i*8+jh]; w2c1[i]=w2w[i*8+jh+4]; }
  float w2b0=w2b[jh], w2b1=w2b[jh+4];
  float A=p2w[lane], B=p2w[64+lane], C2=p2w[128+lane], D=v2w[lane], E=p2b[lane]+v2b[lane];
  int j = lane & 7;
  const float4* renc4 = (const float4*)renc;
  float sr=0.f, sq2=0.f;
  int gw = blockIdx.x*4 + wave;
  for (int n0 = gw; n0 < NPTS; n0 += G4*4){
    int nu = __builtin_amdgcn_readfirstlane(n0);
    const float* w1p = &w1o[(nu*KNN + kq)*8];
    float4 wa = *(const float4*)w1p;
    float4 wb = *(const float4*)(w1p+4);
    float r0 = fmaxf(wa.x*s2[0]+t2[0],0.f);
    float r1 = fmaxf(wa.y*s2[1]+t2[1],0.f);
    float r2 = fmaxf(wa.z*s2[2]+t2[2],0.f);
    float r3 = fmaxf(wa.w*s2[3]+t2[3],0.f);
    float r4 = fmaxf(wb.x*s2[4]+t2[4],0.f);
    float r5 = fmaxf(wb.y*s2[5]+t2[5],0.f);
    float r6 = fmaxf(wb.z*s2[6]+t2[6],0.f);
    float r7 = fmaxf(wb.w*s2[7]+t2[7],0.f);
    float g0 = r0*w2c0[0]+r1*w2c0[1]+r2*w2c0[2]+r3*w2c0[3]
             + r4*w2c0[4]+r5*w2c0[5]+r6*w2c0[6]+r7*w2c0[7] + w2b0;
    float g1 = r0*w2c1[0]+r1*w2c1[1]+r2*w2c1[2]+r3*w2c1[3]
             + r4*w2c1[4]+r5*w2c1[5]+r6*w2c1[6]+r7*w2c1[7] + w2b1;
    float m0 = dpp_max16(g0), m1 = dpp_max16(g1);
    float e0=__expf(g0-m0), e1=__expf(g1-m1);
    float d0 = dpp_sum16(e0), d1 = dpp_sum16(e1);
    sm_s[wave][kq][jh]   = e0/d0;
    sm_s[wave][kq][jh+4] = e1/d1;
    __asm__ __volatile__("" ::: "memory");
    float acc=0.f;
    #pragma unroll 4
    for (int k=0;k<KNN;k++){
      int pu = nu*KNN+k;
      int m = idx[pu];
      float4 rr = renc4[pu];
      float e = rr.x*A + rr.y*B + rr.z*C2 + rr.w*D + E;
      acc += (xv[m*64+lane] + e) * sm_s[wave][k][j];
    }
    float o = acc + feat[nu*64+lane];
    outpre[nu*64+lane] = o;
    sr += o; sq2 += o*o;
    __asm__ __volatile__("" ::: "memory");
  }
  rs[wave][lane]=sr; rq[wave][lane]=sq2;
  __syncthreads();
  if (tid<64){
    float s=rs[0][tid]+rs[1][tid]+rs[2][tid]+rs[3][tid];
    float q=rq[0][tid]+rq[1][tid]+rq[2][tid]+rq[3][tid];
    part4[blockIdx.x*128+tid]=s;
    part4[blockIdx.x*128+64+tid]=q;
  }
}

// ---------------- K5: out = relu(bn_rho(out_pre)) @ rho_w + rho_b ----------------
__global__ __launch_bounds__(256) void k5_rho(
    const float* __restrict__ outpre, const float* __restrict__ stats,
    const float* __restrict__ rhow, const float* __restrict__ rhob,
    float* __restrict__ out)
{
  __shared__ __attribute__((aligned(16))) float4 lw4[1024];
  __shared__ __attribute__((aligned(16))) float lf[2048];
  float* lw = (float*)lw4;
  int tid=threadIdx.x;
  for (int i=tid;i<1024;i+=256) lw4[i] = ((const float4*)rhow)[i];
  __syncthreads();
  int lane=tid&63, wave=tid>>6;
  int nb = blockIdx.x*32 + wave*8;
  float scl = stats[152+lane], sft = stats[216+lane];
  #pragma unroll
  for (int r=0;r<8;r++){
    float a = outpre[(nb+r)*64+lane];
    lf[wave*512 + r*64 + lane] = fmaxf(a*scl+sft, 0.f);
  }
  float acc[8];
  #pragma unroll
  for (int r=0;r<8;r++) acc[r]=0.f;
  for (int i=0;i<64;i+=4){
    float4 fr[8];
    #pragma unroll
    for (int r=0;r<8;r++) fr[r] = *(const float4*)&lf[wave*512 + r*64 + i];
    #pragma unroll
    for (int ii=0;ii<4;ii++){
      float w_ = lw[(i+ii)*64+lane];
      #pragma unroll
      for (int r=0;r<8;r++){
        float f = ii==0?fr[r].x: ii==1?fr[r].y: ii==2?fr[r].z: fr[r].w;
        acc[r] += f*w_;
      }
    }
  }
  float bl = rhob[lane];
  #pragma unroll
  for (int r=0;r<8;r++) out[(nb+r)*64+lane] = acc[r] + bl;
}

extern "C" void kernel_launch(void* const* d_in, const int* in_sizes, int n_in,
                              void* d_out, int out_size, void* d_ws, size_t ws_size,
                              hipStream_t stream) {
  const float* xyz  = (const float*)d_in[0];
  const float* feat = (const float*)d_in[1];
  const float* vel  = (const float*)d_in[2];
  const float* wq   = (const float*)d_in[3];  const float* bq = (const float*)d_in[4];
  const float* wk   = (const float*)d_in[5];  const float* bk = (const float*)d_in[6];
  const float* wv   = (const float*)d_in[7];  const float* bv = (const float*)d_in[8];
  const float* p1w  = (const float*)d_in[9];  const float* p1b = (const float*)d_in[10];
  const float* pbg  = (const float*)d_in[11]; const float* pbb = (const float*)d_in[12];
  const float* p2w  = (const float*)d_in[13]; const float* p2b = (const float*)d_in[14];
  const float* v1w  = (const float*)d_in[15]; const float* v1b = (const float*)d_in[16];
  const float* vbg  = (const float*)d_in[17]; const float* vbb = (const float*)d_in[18];
  const float* v2w  = (const float*)d_in[19]; const float* v2b = (const float*)d_in[20];
  const float* wbn1g= (const float*)d_in[21]; const float* wbn1b= (const float*)d_in[22];
  const float* w1w  = (const float*)d_in[23]; const float* w1b = (const float*)d_in[24];
  const float* wbn2g= (const float*)d_in[25]; const float* wbn2b= (const float*)d_in[26];
  const float* w2w  = (const float*)d_in[27]; const float* w2b = (const float*)d_in[28];
  const float* rbg  = (const float*)d_in[29]; const float* rbb = (const float*)d_in[30];
  const float* rhow = (const float*)d_in[31]; const float* rhob = (const float*)d_in[32];
  const int* idx    = (const int*)d_in[33];
  const int* idxv   = (const int*)d_in[34];

  float* ws = (float*)d_ws;
  float* xq     = ws;
  float* xk     = xq + (size_t)NPTS*CH;
  float* xv     = xk + (size_t)NPTS*CH;
  float* w1o    = xv + (size_t)NPTS*CH;
  float* outpre = w1o + (size_t)NKP*CS;
  float* renc   = outpre + (size_t)NPTS*CH;
  float* part1  = renc + (size_t)NKP*4;
  float* part2  = part1 + G1*8;
  float* part3  = part2 + (size_t)G2*128;
  float* part4  = part3 + G3*16;
  float* stats  = part4 + (size_t)G4*128;

  k1_qkv_stats<<<dim3(G1), dim3(256), 0, stream>>>(
      feat, wq,bq,wk,bk,wv,bv, xyz, vel, p1w,p1b,v1w,v1b, idx, idxv, xq,xk,xv, part1);
  r1_finalize_t<G1><<<dim3(1), dim3(1024), 0, stream>>>(part1, pbg,pbb, vbg,vbb, stats);
  k1b_renc<<<dim3(NKP/256), dim3(256), 0, stream>>>(
      xyz, vel, p1w,p1b, v1w,v1b, idx, idxv, stats, renc);
  k2_wstats<<<dim3(G2), dim3(256), 0, stream>>>(
      idx, renc, p2w,p2b,v2w,v2b, xq, xk, part2);
  finalize_bn_t<G2,64><<<dim3(1), dim3(1024), 0, stream>>>(
      part2, 1.f/(float)NKP, wbn1g, wbn1b, stats+8, stats+72);
  k3_w1<<<dim3(G3), dim3(256), 0, stream>>>(
      p2w,p2b,v2w,v2b, w1w,w1b, idx, renc, xq, xk, stats, w1o, part3);
  finalize_bn_t<G3,8><<<dim3(1), dim3(1024), 0, stream>>>(
      part3, 1.f/(float)NKP, wbn2g, wbn2b, stats+136, stats+144);
  k4_agg<<<dim3(G4), dim3(256), 0, stream>>>(
      feat, p2w,p2b,v2w,v2b, w2w,w2b, idx, renc, xv, w1o, stats, outpre, part4);
  finalize_bn_t<G4,64><<<dim3(1), dim3(1024), 0, stream>>>(
      part4, 1.f/(float)NPTS, rbg, rbb, stats+152, stats+216);
  k5_rho<<<dim3(G5), dim3(256), 0, stream>>>(outpre, stats, rhow, rhob, (float*)d_out);

  (void)in_sizes; (void)n_in; (void)out_size; (void)ws_size;
}